// Round 11
// baseline (191.022 us; speedup 1.0000x reference)
//
#include <hip/hip_runtime.h>
#include <math.h>

typedef __bf16 bf16;
typedef __attribute__((ext_vector_type(8))) __bf16 bf16x8;
typedef __attribute__((ext_vector_type(4))) __bf16 bf16x4;
typedef __attribute__((ext_vector_type(4))) float f32x4;

#define NHEADS 12
#define HDIM 64
#define BATCH 4
#define SEQ 2048
#define CDIM 768
#define MTOK (BATCH * SEQ)                    // 8192 tokens
#define PERPART ((size_t)MTOK * CDIM)         // 6291456 elems
#define NBH (BATCH * NHEADS)                  // 48
#define NKB (SEQ / 64)                        // 32 key blocks of 64, full sweep

// K pre-scale: log2(e)/8 -> softmax exp becomes a single 2^x
#define KSCALE 0.18033688011112042f
// constant shift inside exp2 (cancels exactly in normalization)
#define SHIFT 11.54156032f

// async 16B global->LDS DMA (gfx950). lds ptr wave-uniform; HW adds lane*16.
// One wave-instruction covers 64 granules = 1024 B = 512 bf16 elements.
__device__ static inline void load_lds_16(const void* g, void* l)
{
    __builtin_amdgcn_global_load_lds(
        (const __attribute__((address_space(1))) unsigned int*)g,
        (__attribute__((address_space(3))) unsigned int*)l, 16, 0, 0);
}

// ---------------------------------------------------------------------------
// fused prep: grid-partitioned single kernel.
//   blocks [0, 3072)        : fp32 -> bf16 convert of x (8 elems/thread)
//   blocks [3072, 3504)     : transpose+convert Wqkv  [768][2304] -> [2304][768]
//   blocks [3504, 3648)     : transpose+convert Wproj [768][768]  -> [768][768]
// ---------------------------------------------------------------------------
__global__ __launch_bounds__(256)
void prep(const float* __restrict__ x, const float* __restrict__ Wqkv,
          const float* __restrict__ Wproj,
          bf16* __restrict__ xb, bf16* __restrict__ wqt, bf16* __restrict__ wpt)
{
    __shared__ bf16 T[64][65];
    const int bid = blockIdx.x;
    const int t   = threadIdx.x;

    if (bid < 3072) {
        const size_t i = ((size_t)bid * 256 + t) * 8;
        const float4 v0 = *(const float4*)(x + i);
        const float4 v1 = *(const float4*)(x + i + 4);
        alignas(16) bf16 o[8];
        o[0] = (bf16)v0.x; o[1] = (bf16)v0.y; o[2] = (bf16)v0.z; o[3] = (bf16)v0.w;
        o[4] = (bf16)v1.x; o[5] = (bf16)v1.y; o[6] = (bf16)v1.z; o[7] = (bf16)v1.w;
        *(uint4*)(xb + i) = *(const uint4*)o;
        return;
    }

    const float* in; bf16* outp; int C, bx, by;
    if (bid < 3072 + 432) {
        const int b2 = bid - 3072;
        in = Wqkv; outp = wqt; C = 3 * CDIM; bx = b2 % 36; by = b2 / 36;
    } else {
        const int b2 = bid - 3504;
        in = Wproj; outp = wpt; C = CDIM;    bx = b2 % 12; by = b2 / 12;
    }
    const int r0 = by * 64, c0 = bx * 64;
    const int ir = t >> 2, ic = (t & 3) * 16;
    #pragma unroll
    for (int e = 0; e < 16; ++e)
        T[ir][ic + e] = (bf16)in[(size_t)(r0 + ir) * C + c0 + ic + e];
    __syncthreads();
    const int oc = t >> 2, orr = (t & 3) * 16;
    alignas(16) bf16 tmp[16];
    #pragma unroll
    for (int e = 0; e < 16; ++e)
        tmp[e] = T[orr + e][oc];
    bf16* dst = outp + (size_t)(c0 + oc) * CDIM + r0 + orr;   // R == CDIM
    *(uint4*)dst       = *(const uint4*)tmp;
    *(uint4*)(dst + 8) = *(const uint4*)(tmp + 8);
}

// ---------------------------------------------------------------------------
// QKV GEMM v16: 128x192 tile, BK=32, prefetch DOUBLE-BUFFER.
// Isolates the prefetch mechanism from v11's confound: 24 MFMA per barrier
// (equal to v10/v15's per-barrier average) and 24 total barriers (equal),
// but the vmcnt(0) drain inside each __syncthreads now lands AFTER the
// 24-MFMA compute phase instead of right after load issue.
// LDS 2x(128+192)x32x2B = 40KB; (256,3) reg cap ~170 (acc 96 + frags 40).
// Epilogue -> q, k(*log2e/8), vT bf16 (key-permuted).
// ---------------------------------------------------------------------------
__global__ __launch_bounds__(256, 3)
void gemm_qkv(const bf16* __restrict__ A, const bf16* __restrict__ Bt,
              bf16* __restrict__ qb, bf16* __restrict__ kb,
              bf16* __restrict__ vtb)
{
    constexpr int BN = 192, NT = 6;
    __shared__ bf16 As[2][128 * 32];
    __shared__ bf16 Bs[2][BN * 32];

    const int t    = threadIdx.x;
    const int w    = t >> 6, lane = t & 63;
    const int ln   = lane & 15, quad = lane >> 4;
    const int wr   = w >> 1, wc = w & 1;
    const int m0   = blockIdx.x * 128, n0 = blockIdx.y * BN;

    // staging geometry (16B granules, 4 per 32-col row)
    // A: 512 granules, 2 inst/wave; B: 768 granules, 3 inst/wave
    int arow[2], ag[2], brow[3], bg[3];
    #pragma unroll
    for (int i = 0; i < 2; ++i) {
        const int S = w * 128 + i * 64 + lane;
        arow[i] = S >> 2; ag[i] = (S & 3) ^ (arow[i] & 3);
    }
    #pragma unroll
    for (int i = 0; i < 3; ++i) {
        const int S = w * 192 + i * 64 + lane;
        brow[i] = S >> 2; bg[i] = (S & 3) ^ (brow[i] & 3);
    }

    f32x4 acc[4][NT] = {};

    // prologue: stage K-step 0 into buf 0
    #pragma unroll
    for (int i = 0; i < 2; ++i)
        load_lds_16(A + (size_t)(m0 + arow[i]) * CDIM + ag[i] * 8,
                    &As[0][(w * 2 + i) * 512]);
    #pragma unroll
    for (int i = 0; i < 3; ++i)
        load_lds_16(Bt + (size_t)(n0 + brow[i]) * CDIM + bg[i] * 8,
                    &Bs[0][(w * 3 + i) * 512]);
    __syncthreads();

    const int NSTEP = CDIM / 32;               // 24
    for (int s = 0; s < NSTEP; ++s) {
        // prefetch K-step s+1 (drains at the barrier AFTER this step's MFMAs)
        if (s + 1 < NSTEP) {
            const int nb = (s + 1) & 1, k0 = (s + 1) * 32;
            #pragma unroll
            for (int i = 0; i < 2; ++i)
                load_lds_16(A + (size_t)(m0 + arow[i]) * CDIM + k0 + ag[i] * 8,
                            &As[nb][(w * 2 + i) * 512]);
            #pragma unroll
            for (int i = 0; i < 3; ++i)
                load_lds_16(Bt + (size_t)(n0 + brow[i]) * CDIM + k0 + bg[i] * 8,
                            &Bs[nb][(w * 3 + i) * 512]);
        }

        const bf16* Asb = As[s & 1];
        const bf16* Bsb = Bs[s & 1];

        bf16x8 af[4], bf_[NT];
        #pragma unroll
        for (int mt = 0; mt < 4; ++mt) {
            const int row = wr * 64 + mt * 16 + ln;
            af[mt] = *(const bf16x8*)&Asb[row * 32 + (quad ^ (row & 3)) * 8];
        }
        #pragma unroll
        for (int nt = 0; nt < NT; ++nt) {
            const int row = wc * (BN / 2) + nt * 16 + ln;
            bf_[nt] = *(const bf16x8*)&Bsb[row * 32 + (quad ^ (row & 3)) * 8];
        }
        #pragma unroll
        for (int mt = 0; mt < 4; ++mt)
            #pragma unroll
            for (int nt = 0; nt < NT; ++nt)
                acc[mt][nt] = __builtin_amdgcn_mfma_f32_16x16x32_bf16(
                    af[mt], bf_[nt], acc[mt][nt], 0, 0, 0);

        __syncthreads();   // drains prefetch (overlapped with the MFMAs above)
    }

    #pragma unroll
    for (int nt = 0; nt < NT; ++nt) {
        const int c = n0 + wc * (BN / 2) + nt * 16 + ln;
        const int p = c / CDIM, rem = c - p * CDIM;
        const int h = rem >> 6, d = rem & 63;
        #pragma unroll
        for (int mt = 0; mt < 4; ++mt) {
            const int row0 = m0 + wr * 64 + mt * 16 + quad * 4;
            const int b = row0 >> 11, nn = row0 & 2047;
            if (p == 0) {
                bf16* dst = qb + ((size_t)(b * NHEADS + h) * SEQ + nn) * HDIM + d;
                #pragma unroll
                for (int r = 0; r < 4; ++r) dst[r * HDIM] = (bf16)acc[mt][nt][r];
            } else if (p == 1) {
                bf16* dst = kb + ((size_t)(b * NHEADS + h) * SEQ + nn) * HDIM + d;
                #pragma unroll
                for (int r = 0; r < 4; ++r) dst[r * HDIM] = (bf16)(acc[mt][nt][r] * KSCALE);
            } else {
                // key-permuted V^T: within each 32-key group,
                // j = ((n>>2)&3)*8 + ((n>>4)&1)*4 + (n&3)
                // so a lane's 8-element PV B-fragment is one 16B LDS read.
                alignas(8) bf16 pk[4];
                #pragma unroll
                for (int r = 0; r < 4; ++r) pk[r] = (bf16)acc[mt][nt][r];
                const int nn2 = (nn & ~31) + ((nn >> 2) & 3) * 8 + ((nn >> 4) & 1) * 4;
                *(uint2*)(vtb + ((size_t)(b * NHEADS + h) * HDIM + d) * SEQ + nn2) =
                    *(const uint2*)pk;
            }
        }
    }
}

// ---------------------------------------------------------------------------
// proj GEMM (v15, unchanged): 128x96 tile, BK=64 single-buffer, 1-phase.
// (64,8) = 512 blocks = exactly 2/CU uniform.
// ---------------------------------------------------------------------------
__global__ __launch_bounds__(256, 3)
void gemm_proj(const bf16* __restrict__ A, const bf16* __restrict__ Bt,
               const float* __restrict__ bias, float* __restrict__ outf)
{
    constexpr int BN = 96, NT = 3;
    __shared__ bf16 As[128 * 64];
    __shared__ bf16 Bs[BN * 64];

    const int t    = threadIdx.x;
    const int w    = t >> 6, lane = t & 63;
    const int ln   = lane & 15, quad = lane >> 4;
    const int wr   = w >> 1, wc = w & 1;
    const int m0   = blockIdx.x * 128, n0 = blockIdx.y * BN;

    f32x4 acc[4][NT] = {};

    for (int k0 = 0; k0 < CDIM; k0 += 64) {
        #pragma unroll
        for (int i = 0; i < 4; ++i) {
            const int S   = w * 256 + i * 64 + lane;
            const int row = S >> 3, g = (S & 7) ^ (row & 7);
            load_lds_16(A + (size_t)(m0 + row) * CDIM + k0 + g * 8,
                        &As[(w * 4 + i) * 512]);
        }
        #pragma unroll
        for (int i = 0; i < NT; ++i) {
            const int S   = w * (BN * 2) + i * 64 + lane;
            const int row = S >> 3, g = (S & 7) ^ (row & 7);
            load_lds_16(Bt + (size_t)(n0 + row) * CDIM + k0 + g * 8,
                        &Bs[(w * NT + i) * 512]);
        }
        __syncthreads();

        #pragma unroll
        for (int kk = 0; kk < 2; ++kk) {
            bf16x8 af[4], bf_[NT];
            #pragma unroll
            for (int mt = 0; mt < 4; ++mt) {
                const int row = wr * 64 + mt * 16 + ln;
                af[mt] = *(const bf16x8*)&As[row * 64 + ((kk * 4 + quad) ^ (row & 7)) * 8];
            }
            #pragma unroll
            for (int nt = 0; nt < NT; ++nt) {
                const int row = wc * (BN / 2) + nt * 16 + ln;
                bf_[nt] = *(const bf16x8*)&Bs[row * 64 + ((kk * 4 + quad) ^ (row & 7)) * 8];
            }
            #pragma unroll
            for (int mt = 0; mt < 4; ++mt)
                #pragma unroll
                for (int nt = 0; nt < NT; ++nt)
                    acc[mt][nt] = __builtin_amdgcn_mfma_f32_16x16x32_bf16(
                        af[mt], bf_[nt], acc[mt][nt], 0, 0, 0);
        }
        __syncthreads();
    }

    #pragma unroll
    for (int nt = 0; nt < NT; ++nt) {
        const int c = n0 + wc * (BN / 2) + nt * 16 + ln;
        const float bv = bias[c];
        #pragma unroll
        for (int mt = 0; mt < 4; ++mt) {
            const int row0 = m0 + wr * 64 + mt * 16 + quad * 4;
            #pragma unroll
            for (int r = 0; r < 4; ++r)
                outf[(size_t)(row0 + r) * CDIM + c] = acc[mt][nt][r] + bv;
        }
    }
}

// ---------------------------------------------------------------------------
// Flash attention (v10, unchanged): 64-key K/V tiles, 32KB LDS double buffer,
// 4-wave blocks, grid 768 = 3/CU uniform, raw v_exp_f32, fused
// normalization, XCD swizzle, s_setprio around the rowsum+PV MFMA cluster.
// ---------------------------------------------------------------------------
__global__ __launch_bounds__(256, 4)
void attn_kernel(const bf16* __restrict__ Qg, const bf16* __restrict__ Kg,
                 const bf16* __restrict__ Vtg, bf16* __restrict__ ao)
{
    __shared__ bf16 Ks[2][64 * 64];        // [key][d], double-buffered (8KB ea)
    __shared__ bf16 Vs[2][64 * 64];        // [d][key-permuted], double-buffered

    // bijective swizzle for 768 = 8 XCDs x 96 blocks (round-robin dispatch):
    // XCD c gets virt in [96c, 96c+96) -> bh in [6c, 6c+6), all q-tiles.
    const int virt = (blockIdx.x & 7) * 96 + (blockIdx.x >> 3);
    const int xq   = virt & 15;            // q-tile
    const int bh   = virt >> 4;            // batch*head

    const int t    = threadIdx.x;
    const int w    = t >> 6, lane = t & 63;
    const int ln   = lane & 15, quad = lane >> 4;
    const int q0   = xq * 128;

    const bf16* Qb = Qg  + (size_t)bh * SEQ * HDIM;
    const bf16* Kb = Kg  + (size_t)bh * SEQ * HDIM;
    const bf16* Vb = Vtg + (size_t)bh * HDIM * SEQ;

    // Q fragments straight from global (16B aligned, one-time); wave w owns
    // q rows q0 + w*32 .. +31
    bf16x8 qf[2][2];
    #pragma unroll
    for (int qt = 0; qt < 2; ++qt)
        #pragma unroll
        for (int kk = 0; kk < 2; ++kk) {
            const int row = w * 32 + qt * 16 + ln;
            qf[qt][kk] = *(const bf16x8*)(Qb + (size_t)(q0 + row) * HDIM
                                          + (kk * 4 + quad) * 8);
        }

    // stage key-block 0 into buf 0 (512 granules per 8KB tile, 2 per wave)
    #pragma unroll
    for (int i = 0; i < 2; ++i) {
        const int S = w * 128 + i * 64 + lane;
        const int row = S >> 3, g = (S & 7) ^ (row & 7);
        load_lds_16(Kb + (size_t)row * HDIM + g * 8, &Ks[0][(w * 2 + i) * 512]);
        load_lds_16(Vb + (size_t)row * SEQ + g * 8,  &Vs[0][(w * 2 + i) * 512]);
    }
    __syncthreads();

    bf16x8 ones;
    #pragma unroll
    for (int e = 0; e < 8; ++e) ones[e] = (bf16)1.0f;

    f32x4 o_acc[2][4] = {};
    f32x4 racc[2] = {};                    // row sums, C-layout rows = quad*4+r

    for (int kb = 0; kb < NKB; ++kb) {
        // prefetch next key-block (drains at barrier below, overlapped)
        if (kb + 1 < NKB) {
            const int nb   = (kb + 1) & 1;
            const int kpos = (kb + 1) * 64;
            #pragma unroll
            for (int i = 0; i < 2; ++i) {
                const int S = w * 128 + i * 64 + lane;
                const int row = S >> 3, g = (S & 7) ^ (row & 7);
                load_lds_16(Kb + (size_t)(kpos + row) * HDIM + g * 8,
                            &Ks[nb][(w * 2 + i) * 512]);
                load_lds_16(Vb + (size_t)row * SEQ + kpos + g * 8,
                            &Vs[nb][(w * 2 + i) * 512]);
            }
        }

        const bf16* Ksb = Ks[kb & 1];
        const bf16* Vsb = Vs[kb & 1];

        #pragma unroll
        for (int p = 0; p < 2; ++p) {          // pair of 16-key tiles
            union { bf16x8 v8; bf16x4 v4[2]; } pf8[2];
            #pragma unroll
            for (int sub = 0; sub < 2; ++sub) {
                const int mt = p * 2 + sub;
                bf16x8 ka[2];
                #pragma unroll
                for (int kk = 0; kk < 2; ++kk) {
                    const int row = mt * 16 + ln;
                    const int g = (kk * 4 + quad) ^ (row & 7);
                    ka[kk] = *(const bf16x8*)&Ksb[row * 64 + g * 8];
                }
                #pragma unroll
                for (int qt = 0; qt < 2; ++qt) {
                    f32x4 a = {-SHIFT, -SHIFT, -SHIFT, -SHIFT};
                    a = __builtin_amdgcn_mfma_f32_16x16x32_bf16(ka[0], qf[qt][0], a, 0, 0, 0);
                    a = __builtin_amdgcn_mfma_f32_16x16x32_bf16(ka[1], qf[qt][1], a, 0, 0, 0);
                    // raw v_exp_f32: ~1 ulp, flushes the softmax tail to 0.
                    bf16x4 pb = { (bf16)__builtin_amdgcn_exp2f(a[0]),
                                  (bf16)__builtin_amdgcn_exp2f(a[1]),
                                  (bf16)__builtin_amdgcn_exp2f(a[2]),
                                  (bf16)__builtin_amdgcn_exp2f(a[3]) };
                    pf8[qt].v4[sub] = pb;
                }
            }
            // rowsum + PV: pure-MFMA cluster, elevate wave priority (T5)
            __builtin_amdgcn_s_setprio(1);
            #pragma unroll
            for (int qt = 0; qt < 2; ++qt)
                racc[qt] = __builtin_amdgcn_mfma_f32_16x16x32_bf16(
                    pf8[qt].v8, ones, racc[qt], 0, 0, 0);
            #pragma unroll
            for (int dt = 0; dt < 4; ++dt) {
                const int row = dt * 16 + ln;               // d
                const int g = (p * 4 + quad) ^ (row & 7);
                const bf16x8 vvv = *(const bf16x8*)&Vsb[row * 64 + g * 8];
                #pragma unroll
                for (int qt = 0; qt < 2; ++qt)
                    o_acc[qt][dt] = __builtin_amdgcn_mfma_f32_16x16x32_bf16(
                        pf8[qt].v8, vvv, o_acc[qt][dt], 0, 0, 0);
            }
            __builtin_amdgcn_s_setprio(0);
        }
        __syncthreads();   // drains prefetch (overlapped) + guards buffer swap
    }

    // epilogue: fused softmax normalization, write straight to attention
    // output layout ao[b][q][h*64+d] (f32 divide, single bf16 rounding).
    const int b = bh / NHEADS, h = bh - b * NHEADS;
    bf16* Ao = ao + (size_t)b * SEQ * CDIM + h * HDIM;
    #pragma unroll
    for (int qt = 0; qt < 2; ++qt) {
        float inv[4];
        #pragma unroll
        for (int r = 0; r < 4; ++r) inv[r] = 1.0f / racc[qt][r];
        #pragma unroll
        for (int dt = 0; dt < 4; ++dt) {
            const int d = dt * 16 + ln;
            #pragma unroll
            for (int r = 0; r < 4; ++r) {
                const int q = q0 + w * 32 + qt * 16 + quad * 4 + r;
                Ao[(size_t)q * CDIM + d] = (bf16)(o_acc[qt][dt][r] * inv[r]);
            }
        }
    }
}

// ---------------------------------------------------------------------------
extern "C" void kernel_launch(void* const* d_in, const int* in_sizes, int n_in,
                              void* d_out, int out_size, void* d_ws, size_t ws_size,
                              hipStream_t stream)
{
    const float* x     = (const float*)d_in[0];
    const float* Wqkv  = (const float*)d_in[1];
    const float* Wproj = (const float*)d_in[2];
    const float* bproj = (const float*)d_in[3];
    float* out = (float*)d_out;

    bf16* ws   = (bf16*)d_ws;
    bf16* xb   = ws;                                   // [8192][768]
    bf16* wqt  = xb  + PERPART;                        // [2304][768]
    bf16* wpt  = wqt + (size_t)3 * CDIM * CDIM;        // [768][768]
    bf16* q    = wpt + (size_t)CDIM * CDIM;            // [bh][2048][64]
    bf16* k    = q   + PERPART;                        // scaled by log2e/8
    bf16* vt   = k   + PERPART;                        // [bh][64][2048] key-permuted
    bf16* ao   = vt  + PERPART;                        // [8192][768]

    prep<<<dim3(3072 + 432 + 144), 256, 0, stream>>>(x, Wqkv, Wproj, xb, wqt, wpt);

    // QKV: 128x192 tiles, BK=32 prefetch-dbuf -> (64, 12) = 768 blocks
    gemm_qkv<<<dim3(MTOK / 128, 3 * CDIM / 192), 256, 0, stream>>>(
        xb, wqt, q, k, vt);
    attn_kernel<<<dim3(16 * NBH), 256, 0, stream>>>(q, k, vt, ao);
    // proj: 128x96 tiles -> (64, 8) = 512 blocks = exactly 2/CU uniform
    gemm_proj<<<dim3(MTOK / 128, CDIM / 96), 256, 0, stream>>>(
        ao, wpt, bproj, out);
}

// Round 12
// 184.428 us; speedup vs baseline: 1.0358x; 1.0358x over previous
//
#include <hip/hip_runtime.h>
#include <math.h>

typedef __bf16 bf16;
typedef __attribute__((ext_vector_type(8))) __bf16 bf16x8;
typedef __attribute__((ext_vector_type(4))) __bf16 bf16x4;
typedef __attribute__((ext_vector_type(4))) float f32x4;

#define NHEADS 12
#define HDIM 64
#define BATCH 4
#define SEQ 2048
#define CDIM 768
#define MTOK (BATCH * SEQ)                    // 8192 tokens
#define PERPART ((size_t)MTOK * CDIM)         // 6291456 elems
#define NBH (BATCH * NHEADS)                  // 48
#define NKB (SEQ / 64)                        // 32 key blocks of 64, full sweep

// K pre-scale: log2(e)/8 -> softmax exp becomes a single 2^x
#define KSCALE 0.18033688011112042f
// constant shift inside exp2 (cancels exactly in normalization)
#define SHIFT 11.54156032f

// async 16B global->LDS DMA (gfx950). lds ptr wave-uniform; HW adds lane*16.
// One wave-instruction covers 64 granules = 1024 B = 512 bf16 elements.
__device__ static inline void load_lds_16(const void* g, void* l)
{
    __builtin_amdgcn_global_load_lds(
        (const __attribute__((address_space(1))) unsigned int*)g,
        (__attribute__((address_space(3))) unsigned int*)l, 16, 0, 0);
}

// ---------------------------------------------------------------------------
// fused prep: grid-partitioned single kernel.
//   blocks [0, 3072)        : fp32 -> bf16 convert of x (8 elems/thread)
//   blocks [3072, 3504)     : transpose+convert Wqkv  [768][2304] -> [2304][768]
//   blocks [3504, 3648)     : transpose+convert Wproj [768][768]  -> [768][768]
// ---------------------------------------------------------------------------
__global__ __launch_bounds__(256)
void prep(const float* __restrict__ x, const float* __restrict__ Wqkv,
          const float* __restrict__ Wproj,
          bf16* __restrict__ xb, bf16* __restrict__ wqt, bf16* __restrict__ wpt)
{
    __shared__ bf16 T[64][65];
    const int bid = blockIdx.x;
    const int t   = threadIdx.x;

    if (bid < 3072) {
        const size_t i = ((size_t)bid * 256 + t) * 8;
        const float4 v0 = *(const float4*)(x + i);
        const float4 v1 = *(const float4*)(x + i + 4);
        alignas(16) bf16 o[8];
        o[0] = (bf16)v0.x; o[1] = (bf16)v0.y; o[2] = (bf16)v0.z; o[3] = (bf16)v0.w;
        o[4] = (bf16)v1.x; o[5] = (bf16)v1.y; o[6] = (bf16)v1.z; o[7] = (bf16)v1.w;
        *(uint4*)(xb + i) = *(const uint4*)o;
        return;
    }

    const float* in; bf16* outp; int C, bx, by;
    if (bid < 3072 + 432) {
        const int b2 = bid - 3072;
        in = Wqkv; outp = wqt; C = 3 * CDIM; bx = b2 % 36; by = b2 / 36;
    } else {
        const int b2 = bid - 3504;
        in = Wproj; outp = wpt; C = CDIM;    bx = b2 % 12; by = b2 / 12;
    }
    const int r0 = by * 64, c0 = bx * 64;
    const int ir = t >> 2, ic = (t & 3) * 16;
    #pragma unroll
    for (int e = 0; e < 16; ++e)
        T[ir][ic + e] = (bf16)in[(size_t)(r0 + ir) * C + c0 + ic + e];
    __syncthreads();
    const int oc = t >> 2, orr = (t & 3) * 16;
    alignas(16) bf16 tmp[16];
    #pragma unroll
    for (int e = 0; e < 16; ++e)
        tmp[e] = T[orr + e][oc];
    bf16* dst = outp + (size_t)(c0 + oc) * CDIM + r0 + orr;   // R == CDIM
    *(uint4*)dst       = *(const uint4*)tmp;
    *(uint4*)(dst + 8) = *(const uint4*)(tmp + 8);
}

// ---------------------------------------------------------------------------
// GEMM: 128 x BN tile, BK=64 single-buffer, 1-phase (the proven optimum of
// the explored space). QKV: BN=192 -> (64,12)=768 blocks. Proj: BN=96 ->
// (64,8)=512 blocks = exactly 2/CU uniform (BN=128's 1.5/CU lost ~25%
// makespan). launch_bounds(256,3). Measured-worse alternatives: BK=32
// prefetch-dbuf (v11 bundled, v16 confound-free), (256,4) cap (v12).
// MODE 0: QKV epilogue -> q, k(*log2e/8), vT bf16 (key-permuted).
// MODE 1: proj epilogue -> + bias, fp32 out.
// ---------------------------------------------------------------------------
template<int BN, int MODE>
__global__ __launch_bounds__(256, 3)
void gemm128(const bf16* __restrict__ A, const bf16* __restrict__ Bt,
             const float* __restrict__ bias,
             bf16* __restrict__ qb, bf16* __restrict__ kb, bf16* __restrict__ vtb,
             float* __restrict__ outf)
{
    constexpr int NT = BN / 32;            // acc tiles per wave in N (BN/2/16)
    __shared__ bf16 As[128 * 64];
    __shared__ bf16 Bs[BN * 64];

    const int t    = threadIdx.x;
    const int w    = t >> 6, lane = t & 63;
    const int ln   = lane & 15, quad = lane >> 4;
    const int wr   = w >> 1, wc = w & 1;
    const int m0   = blockIdx.x * 128, n0 = blockIdx.y * BN;

    f32x4 acc[4][NT] = {};

    for (int k0 = 0; k0 < CDIM; k0 += 64) {
        // stage A 128x64 (1024 granules) + Bt BNx64 (BN*8 granules)
        #pragma unroll
        for (int i = 0; i < 4; ++i) {
            const int S   = w * 256 + i * 64 + lane;
            const int row = S >> 3, g = (S & 7) ^ (row & 7);
            load_lds_16(A + (size_t)(m0 + row) * CDIM + k0 + g * 8,
                        &As[(w * 4 + i) * 512]);
        }
        #pragma unroll
        for (int i = 0; i < NT; ++i) {         // BN*8/4waves/64lanes = NT instr
            const int S   = w * (BN * 2) + i * 64 + lane;
            const int row = S >> 3, g = (S & 7) ^ (row & 7);
            load_lds_16(Bt + (size_t)(n0 + row) * CDIM + k0 + g * 8,
                        &Bs[(w * NT + i) * 512]);
        }
        __syncthreads();

        #pragma unroll
        for (int kk = 0; kk < 2; ++kk) {
            bf16x8 af[4], bf_[NT];
            #pragma unroll
            for (int mt = 0; mt < 4; ++mt) {
                const int row = wr * 64 + mt * 16 + ln;
                af[mt] = *(const bf16x8*)&As[row * 64 + ((kk * 4 + quad) ^ (row & 7)) * 8];
            }
            #pragma unroll
            for (int nt = 0; nt < NT; ++nt) {
                const int row = wc * (BN / 2) + nt * 16 + ln;
                bf_[nt] = *(const bf16x8*)&Bs[row * 64 + ((kk * 4 + quad) ^ (row & 7)) * 8];
            }
            #pragma unroll
            for (int mt = 0; mt < 4; ++mt)
                #pragma unroll
                for (int nt = 0; nt < NT; ++nt)
                    acc[mt][nt] = __builtin_amdgcn_mfma_f32_16x16x32_bf16(
                        af[mt], bf_[nt], acc[mt][nt], 0, 0, 0);
        }
        __syncthreads();
    }

    #pragma unroll
    for (int nt = 0; nt < NT; ++nt) {
        const int c = n0 + wc * (BN / 2) + nt * 16 + ln;
        if constexpr (MODE == 0) {
            const int p = c / CDIM, rem = c - p * CDIM;
            const int h = rem >> 6, d = rem & 63;
            #pragma unroll
            for (int mt = 0; mt < 4; ++mt) {
                const int row0 = m0 + wr * 64 + mt * 16 + quad * 4;
                const int b = row0 >> 11, nn = row0 & 2047;
                if (p == 0) {
                    bf16* dst = qb + ((size_t)(b * NHEADS + h) * SEQ + nn) * HDIM + d;
                    #pragma unroll
                    for (int r = 0; r < 4; ++r) dst[r * HDIM] = (bf16)acc[mt][nt][r];
                } else if (p == 1) {
                    bf16* dst = kb + ((size_t)(b * NHEADS + h) * SEQ + nn) * HDIM + d;
                    #pragma unroll
                    for (int r = 0; r < 4; ++r) dst[r * HDIM] = (bf16)(acc[mt][nt][r] * KSCALE);
                } else {
                    // key-permuted V^T: within each 32-key group,
                    // j = ((n>>2)&3)*8 + ((n>>4)&1)*4 + (n&3)
                    // so a lane's 8-element PV B-fragment is one 16B LDS read.
                    alignas(8) bf16 pk[4];
                    #pragma unroll
                    for (int r = 0; r < 4; ++r) pk[r] = (bf16)acc[mt][nt][r];
                    const int nn2 = (nn & ~31) + ((nn >> 2) & 3) * 8 + ((nn >> 4) & 1) * 4;
                    *(uint2*)(vtb + ((size_t)(b * NHEADS + h) * HDIM + d) * SEQ + nn2) =
                        *(const uint2*)pk;
                }
            }
        } else {
            const float bv = bias[c];
            #pragma unroll
            for (int mt = 0; mt < 4; ++mt) {
                const int row0 = m0 + wr * 64 + mt * 16 + quad * 4;
                #pragma unroll
                for (int r = 0; r < 4; ++r)
                    outf[(size_t)(row0 + r) * CDIM + c] = acc[mt][nt][r] + bv;
            }
        }
    }
}

// ---------------------------------------------------------------------------
// Flash attention (v10, unchanged): 64-key K/V tiles, 32KB LDS double buffer,
// 4-wave blocks, grid 768 = 3/CU uniform, raw v_exp_f32, fused
// normalization, XCD swizzle, s_setprio around the rowsum+PV MFMA cluster.
// ---------------------------------------------------------------------------
__global__ __launch_bounds__(256, 4)
void attn_kernel(const bf16* __restrict__ Qg, const bf16* __restrict__ Kg,
                 const bf16* __restrict__ Vtg, bf16* __restrict__ ao)
{
    __shared__ bf16 Ks[2][64 * 64];        // [key][d], double-buffered (8KB ea)
    __shared__ bf16 Vs[2][64 * 64];        // [d][key-permuted], double-buffered

    // bijective swizzle for 768 = 8 XCDs x 96 blocks (round-robin dispatch):
    // XCD c gets virt in [96c, 96c+96) -> bh in [6c, 6c+6), all q-tiles.
    const int virt = (blockIdx.x & 7) * 96 + (blockIdx.x >> 3);
    const int xq   = virt & 15;            // q-tile
    const int bh   = virt >> 4;            // batch*head

    const int t    = threadIdx.x;
    const int w    = t >> 6, lane = t & 63;
    const int ln   = lane & 15, quad = lane >> 4;
    const int q0   = xq * 128;

    const bf16* Qb = Qg  + (size_t)bh * SEQ * HDIM;
    const bf16* Kb = Kg  + (size_t)bh * SEQ * HDIM;
    const bf16* Vb = Vtg + (size_t)bh * HDIM * SEQ;

    // Q fragments straight from global (16B aligned, one-time); wave w owns
    // q rows q0 + w*32 .. +31
    bf16x8 qf[2][2];
    #pragma unroll
    for (int qt = 0; qt < 2; ++qt)
        #pragma unroll
        for (int kk = 0; kk < 2; ++kk) {
            const int row = w * 32 + qt * 16 + ln;
            qf[qt][kk] = *(const bf16x8*)(Qb + (size_t)(q0 + row) * HDIM
                                          + (kk * 4 + quad) * 8);
        }

    // stage key-block 0 into buf 0 (512 granules per 8KB tile, 2 per wave)
    #pragma unroll
    for (int i = 0; i < 2; ++i) {
        const int S = w * 128 + i * 64 + lane;
        const int row = S >> 3, g = (S & 7) ^ (row & 7);
        load_lds_16(Kb + (size_t)row * HDIM + g * 8, &Ks[0][(w * 2 + i) * 512]);
        load_lds_16(Vb + (size_t)row * SEQ + g * 8,  &Vs[0][(w * 2 + i) * 512]);
    }
    __syncthreads();

    bf16x8 ones;
    #pragma unroll
    for (int e = 0; e < 8; ++e) ones[e] = (bf16)1.0f;

    f32x4 o_acc[2][4] = {};
    f32x4 racc[2] = {};                    // row sums, C-layout rows = quad*4+r

    for (int kb = 0; kb < NKB; ++kb) {
        // prefetch next key-block (drains at barrier below, overlapped)
        if (kb + 1 < NKB) {
            const int nb   = (kb + 1) & 1;
            const int kpos = (kb + 1) * 64;
            #pragma unroll
            for (int i = 0; i < 2; ++i) {
                const int S = w * 128 + i * 64 + lane;
                const int row = S >> 3, g = (S & 7) ^ (row & 7);
                load_lds_16(Kb + (size_t)(kpos + row) * HDIM + g * 8,
                            &Ks[nb][(w * 2 + i) * 512]);
                load_lds_16(Vb + (size_t)row * SEQ + kpos + g * 8,
                            &Vs[nb][(w * 2 + i) * 512]);
            }
        }

        const bf16* Ksb = Ks[kb & 1];
        const bf16* Vsb = Vs[kb & 1];

        #pragma unroll
        for (int p = 0; p < 2; ++p) {          // pair of 16-key tiles
            union { bf16x8 v8; bf16x4 v4[2]; } pf8[2];
            #pragma unroll
            for (int sub = 0; sub < 2; ++sub) {
                const int mt = p * 2 + sub;
                bf16x8 ka[2];
                #pragma unroll
                for (int kk = 0; kk < 2; ++kk) {
                    const int row = mt * 16 + ln;
                    const int g = (kk * 4 + quad) ^ (row & 7);
                    ka[kk] = *(const bf16x8*)&Ksb[row * 64 + g * 8];
                }
                #pragma unroll
                for (int qt = 0; qt < 2; ++qt) {
                    f32x4 a = {-SHIFT, -SHIFT, -SHIFT, -SHIFT};
                    a = __builtin_amdgcn_mfma_f32_16x16x32_bf16(ka[0], qf[qt][0], a, 0, 0, 0);
                    a = __builtin_amdgcn_mfma_f32_16x16x32_bf16(ka[1], qf[qt][1], a, 0, 0, 0);
                    // raw v_exp_f32: ~1 ulp, flushes the softmax tail to 0.
                    bf16x4 pb = { (bf16)__builtin_amdgcn_exp2f(a[0]),
                                  (bf16)__builtin_amdgcn_exp2f(a[1]),
                                  (bf16)__builtin_amdgcn_exp2f(a[2]),
                                  (bf16)__builtin_amdgcn_exp2f(a[3]) };
                    pf8[qt].v4[sub] = pb;
                }
            }
            // rowsum + PV: pure-MFMA cluster, elevate wave priority (T5)
            __builtin_amdgcn_s_setprio(1);
            #pragma unroll
            for (int qt = 0; qt < 2; ++qt)
                racc[qt] = __builtin_amdgcn_mfma_f32_16x16x32_bf16(
                    pf8[qt].v8, ones, racc[qt], 0, 0, 0);
            #pragma unroll
            for (int dt = 0; dt < 4; ++dt) {
                const int row = dt * 16 + ln;               // d
                const int g = (p * 4 + quad) ^ (row & 7);
                const bf16x8 vvv = *(const bf16x8*)&Vsb[row * 64 + g * 8];
                #pragma unroll
                for (int qt = 0; qt < 2; ++qt)
                    o_acc[qt][dt] = __builtin_amdgcn_mfma_f32_16x16x32_bf16(
                        pf8[qt].v8, vvv, o_acc[qt][dt], 0, 0, 0);
            }
            __builtin_amdgcn_s_setprio(0);
        }
        __syncthreads();   // drains prefetch (overlapped) + guards buffer swap
    }

    // epilogue: fused softmax normalization, write straight to attention
    // output layout ao[b][q][h*64+d] (f32 divide, single bf16 rounding).
    const int b = bh / NHEADS, h = bh - b * NHEADS;
    bf16* Ao = ao + (size_t)b * SEQ * CDIM + h * HDIM;
    #pragma unroll
    for (int qt = 0; qt < 2; ++qt) {
        float inv[4];
        #pragma unroll
        for (int r = 0; r < 4; ++r) inv[r] = 1.0f / racc[qt][r];
        #pragma unroll
        for (int dt = 0; dt < 4; ++dt) {
            const int d = dt * 16 + ln;
            #pragma unroll
            for (int r = 0; r < 4; ++r) {
                const int q = q0 + w * 32 + qt * 16 + quad * 4 + r;
                Ao[(size_t)q * CDIM + d] = (bf16)(o_acc[qt][dt][r] * inv[r]);
            }
        }
    }
}

// ---------------------------------------------------------------------------
extern "C" void kernel_launch(void* const* d_in, const int* in_sizes, int n_in,
                              void* d_out, int out_size, void* d_ws, size_t ws_size,
                              hipStream_t stream)
{
    const float* x     = (const float*)d_in[0];
    const float* Wqkv  = (const float*)d_in[1];
    const float* Wproj = (const float*)d_in[2];
    const float* bproj = (const float*)d_in[3];
    float* out = (float*)d_out;

    bf16* ws   = (bf16*)d_ws;
    bf16* xb   = ws;                                   // [8192][768]
    bf16* wqt  = xb  + PERPART;                        // [2304][768]
    bf16* wpt  = wqt + (size_t)3 * CDIM * CDIM;        // [768][768]
    bf16* q    = wpt + (size_t)CDIM * CDIM;            // [bh][2048][64]
    bf16* k    = q   + PERPART;                        // scaled by log2e/8
    bf16* vt   = k   + PERPART;                        // [bh][64][2048] key-permuted
    bf16* ao   = vt  + PERPART;                        // [8192][768]

    prep<<<dim3(3072 + 432 + 144), 256, 0, stream>>>(x, Wqkv, Wproj, xb, wqt, wpt);

    // QKV: 128x192 tiles -> (64, 12) = 768 blocks = 3/CU uniform round
    gemm128<192, 0><<<dim3(MTOK / 128, 3 * CDIM / 192), 256, 0, stream>>>(
        xb, wqt, nullptr, q, k, vt, nullptr);
    attn_kernel<<<dim3(16 * NBH), 256, 0, stream>>>(q, k, vt, ao);
    // proj: 128x96 tiles -> (64, 8) = 512 blocks = exactly 2/CU uniform
    gemm128<96, 1><<<dim3(MTOK / 128, CDIM / 96), 256, 0, stream>>>(
        ao, wpt, bproj, nullptr, nullptr, nullptr, out);
}